// Round 3
// baseline (1050.271 us; speedup 1.0000x reference)
//
#include <hip/hip_runtime.h>
#include <cstdint>

// BloomEmbedding v3: counting-sort gather.
//
// v2 post-mortem: warming the 128 MB table into the 256 MB Infinity Cache did
// NOT speed up the random gather (185 us/hash with warm == 189 us/hash
// without). => the ~550 GB/s random-read wall is NOT DRAM activation; it is
// read-request latency x limited miss concurrency. Writes have no response
// dependency, so we move the randomness to the write side:
//   K1 histogram + K2 scan + K3 scatter: counting-sort 3.276M (key, out_slot)
//      records by table region (8192 buckets x 64 KB).
//   K4 gather: reads table in key-sorted order (streaming-like, duplicates
//      hit L1/L2), writes out[out_slot] as random full-128B-line nt stores.
// Workspace: 26.2 MB records + 64 KB hist/cursor. Falls back to the known-good
// single-kernel path if ws_size is too small.

#define TABLE_SIZE 1000000u
#define SEED 42u
#define NB 8192          // buckets; key < 4e6, key>>9 < 7813
#define BSHIFT 9

typedef float vfloat4 __attribute__((ext_vector_type(4)));

__device__ __forceinline__ uint32_t hash_id(uint32_t x) {
    x ^= x >> 16;
    x *= 0x7FEB352Du;
    x ^= x >> 15;
    x *= 0x846CA68Bu;
    x ^= x >> 16;
    return x % TABLE_SIZE;
}

__global__ void __launch_bounds__(256) zero_kernel(unsigned int* __restrict__ p, int n) {
    int i = blockIdx.x * blockDim.x + threadIdx.x;
    if (i < n) p[i] = 0u;
}

__global__ void __launch_bounds__(256) hist_kernel(const int* __restrict__ ids,
                                                   unsigned int* __restrict__ hist,
                                                   int n) {
    int i = blockIdx.x * blockDim.x + threadIdx.x;
    const int stride = gridDim.x * blockDim.x;
    for (; i < n; i += stride) {
        const uint32_t id = (uint32_t)ids[i];
        #pragma unroll
        for (uint32_t h = 0; h < 4; ++h) {
            const uint32_t key = h * TABLE_SIZE + hash_id(id + SEED + h);
            atomicAdd(&hist[key >> BSHIFT], 1u);
        }
    }
}

// Exclusive scan of NB=8192 counters, one block of 1024 threads, 8 per thread.
__global__ void __launch_bounds__(1024) scan_kernel(const unsigned int* __restrict__ hist,
                                                    unsigned int* __restrict__ cursor) {
    __shared__ unsigned int lds[1024];
    const int t = threadIdx.x;
    unsigned int v[8];
    unsigned int s = 0;
    #pragma unroll
    for (int k = 0; k < 8; ++k) { v[k] = hist[t * 8 + k]; s += v[k]; }
    lds[t] = s;
    __syncthreads();
    for (int off = 1; off < 1024; off <<= 1) {
        unsigned int x = (t >= off) ? lds[t - off] : 0u;
        __syncthreads();
        lds[t] += x;
        __syncthreads();
    }
    unsigned int base = (t == 0) ? 0u : lds[t - 1];   // exclusive prefix
    #pragma unroll
    for (int k = 0; k < 8; ++k) { cursor[t * 8 + k] = base; base += v[k]; }
}

// Scatter records (key, i*4+h) into bucket-major order via atomic cursors.
__global__ void __launch_bounds__(256) scatter_kernel(const int* __restrict__ ids,
                                                      unsigned int* __restrict__ cursor,
                                                      uint2* __restrict__ recs,
                                                      int n) {
    int i = blockIdx.x * blockDim.x + threadIdx.x;
    const int stride = gridDim.x * blockDim.x;
    for (; i < n; i += stride) {
        const uint32_t id = (uint32_t)ids[i];
        #pragma unroll
        for (uint32_t h = 0; h < 4; ++h) {
            const uint32_t key = h * TABLE_SIZE + hash_id(id + SEED + h);
            const unsigned int pos = atomicAdd(&cursor[key >> BSHIFT], 1u);
            recs[pos] = make_uint2(key, ((uint32_t)i << 2) | h);
        }
    }
}

// Gather in key-sorted order: 8 lanes per record move one 128 B row.
// Reads: coarsely ascending (64 KB regions), dups hit cache.
// Writes: random full-line nt stores (no response latency to wait on).
__global__ void __launch_bounds__(256) sorted_gather_kernel(
        const uint2* __restrict__ recs,
        const vfloat4* __restrict__ tab,   // flat [4*1e6][8] float4
        vfloat4* __restrict__ out,
        int R) {
    const int tid = blockIdx.x * blockDim.x + threadIdx.x;
    const int r = tid >> 3;
    if (r >= R) return;
    const int d4 = tid & 7;

    const uint2 rec = recs[r];
    const vfloat4 v = tab[(size_t)rec.x * 8 + (size_t)d4];
    __builtin_nontemporal_store(
        v, &out[(size_t)(rec.y >> 2) * 32 + (size_t)((rec.y & 3u) * 8u + d4)]);
}

// Fallback: known-good single-kernel path (756 us) if workspace is too small.
__global__ void __launch_bounds__(256) bloom_emb_kernel(const int* __restrict__ ids,
                                                        const vfloat4* __restrict__ tables,
                                                        vfloat4* __restrict__ out,
                                                        int n) {
    const int tid = blockIdx.x * blockDim.x + threadIdx.x;
    const int gid = tid >> 5;
    if (gid >= n) return;
    const int lane = tid & 31;
    const int h  = lane >> 3;
    const int d4 = lane & 7;
    const uint32_t idx = hash_id((uint32_t)ids[gid] + SEED + (uint32_t)h);
    const vfloat4 v = tables[((size_t)h * TABLE_SIZE + idx) * 8 + (size_t)d4];
    out[(size_t)gid * 32 + (size_t)lane] = v;
}

extern "C" void kernel_launch(void* const* d_in, const int* in_sizes, int n_in,
                              void* d_out, int out_size, void* d_ws, size_t ws_size,
                              hipStream_t stream) {
    const int*     ids    = (const int*)d_in[0];
    const vfloat4* tables = (const vfloat4*)d_in[1];
    vfloat4*       out    = (vfloat4*)d_out;

    const int n = in_sizes[0];            // 819200 ids
    const int R = n * 4;                  // 3,276,800 records

    const size_t recs_bytes = (size_t)R * 8;
    const size_t need = recs_bytes + 2 * NB * sizeof(unsigned int) + 256;

    if (ws_size < need) {
        // Fallback: baseline gather.
        const long long total = (long long)n * 32;
        const int grid = (int)((total + 255) / 256);
        bloom_emb_kernel<<<grid, 256, 0, stream>>>(ids, tables, out, n);
        return;
    }

    uint2*        recs   = (uint2*)d_ws;
    unsigned int* hist   = (unsigned int*)((char*)d_ws + ((recs_bytes + 255) & ~(size_t)255));
    unsigned int* cursor = hist + NB;

    zero_kernel<<<(NB + 255) / 256, 256, 0, stream>>>(hist, NB);
    hist_kernel<<<2048, 256, 0, stream>>>(ids, hist, n);
    scan_kernel<<<1, 1024, 0, stream>>>(hist, cursor);
    scatter_kernel<<<2048, 256, 0, stream>>>(ids, cursor, recs, n);

    const long long gthreads = (long long)R * 8;
    const int ggrid = (int)((gthreads + 255) / 256);
    sorted_gather_kernel<<<ggrid, 256, 0, stream>>>(recs, tables, out, R);
}